// Round 2
// baseline (105475.574 us; speedup 1.0000x reference)
//
#include <hip/hip_runtime.h>

// ---------------------------------------------------------------------------
// RAFT+DICL correlation module, fp32 reference-faithful baseline.
// Levels L=4, D=9 (81 displacements), C=32, B=2, H=48, W=64.
// Per level: sample -> conv1(64->96) -> conv2(96->128,s2) -> conv3(128->128)
//            -> conv4(128->64) -> deconv(64->32,k4s2) -> conv6(32->1) -> DAP.
//
// NOTE input order is INTERLEAVED per setup_inputs() dict insertion:
//   d_in[0]=fmap1_0, d_in[1]=fmap2_0, d_in[2]=fmap1_1, d_in[3]=fmap2_1, ...
// ---------------------------------------------------------------------------

constexpr int D9   = 9;
constexpr int NB   = 2;
constexpr int HH   = 48;
constexpr int WW   = 64;
constexpr int NIMG = NB * D9 * D9;   // 162
constexpr int HW   = HH * WW;        // 3072

static inline int cdiv(int a, int b) { return (a + b - 1) / b; }

// One thread per (local image, y, x); writes all 64 corr channels.
__global__ void sample_kernel(const float* __restrict__ f1, const float* __restrict__ f2,
                              const float* __restrict__ coords, float* __restrict__ corr,
                              int n0, int nimg, int h2, int w2, float inv_scale)
{
    int idx = blockIdx.x * blockDim.x + threadIdx.x;
    int total = nimg * HW;
    if (idx >= total) return;
    int x = idx % WW;
    int t = idx / WW;
    int y = t % HH;
    int nl = t / HH;
    int ng = n0 + nl;                  // global image index 0..161
    int b   = ng / (D9 * D9);
    int c81 = ng % (D9 * D9);
    int di = c81 / D9;                 // dx index
    int dj = c81 % D9;                 // dy index

    float cx = coords[((size_t)(b * 2 + 0) * HH + y) * WW + x];
    float cy = coords[((size_t)(b * 2 + 1) * HH + y) * WW + x];
    float gx = cx * inv_scale + (float)(di - 4);
    float gy = cy * inv_scale + (float)(dj - 4);

    float x0f = floorf(gx), y0f = floorf(gy);
    float wx = gx - x0f, wy = gy - y0f;
    int x0 = (int)x0f, y0 = (int)y0f;
    int x1 = x0 + 1, y1 = y0 + 1;
    bool vx0 = (x0 >= 0) && (x0 <= w2 - 1);
    bool vx1 = (x1 >= 0) && (x1 <= w2 - 1);
    bool vy0 = (y0 >= 0) && (y0 <= h2 - 1);
    bool vy1 = (y1 >= 0) && (y1 <= h2 - 1);
    int xc0 = min(max(x0, 0), w2 - 1), xc1 = min(max(x1, 0), w2 - 1);
    int yc0 = min(max(y0, 0), h2 - 1), yc1 = min(max(y1, 0), h2 - 1);
    float m00 = (vx0 && vy0) ? (1.f - wx) * (1.f - wy) : 0.f;
    float m10 = (vx1 && vy0) ? wx * (1.f - wy) : 0.f;
    float m01 = (vx0 && vy1) ? (1.f - wx) * wy : 0.f;
    float m11 = (vx1 && vy1) ? wx * wy : 0.f;

    const float* f1b = f1 + ((size_t)b * 32) * HW + (size_t)y * WW + x;
    const float* f2b = f2 + (size_t)b * 32 * h2 * w2;
    float* outb = corr + (size_t)nl * 64 * HW + (size_t)y * WW + x;

    #pragma unroll 8
    for (int ch = 0; ch < 32; ++ch)
        outb[(size_t)ch * HW] = f1b[(size_t)ch * HW];

    int o00 = yc0 * w2 + xc0, o10 = yc0 * w2 + xc1;
    int o01 = yc1 * w2 + xc0, o11 = yc1 * w2 + xc1;
    #pragma unroll 4
    for (int ch = 0; ch < 32; ++ch) {
        const float* im = f2b + (size_t)ch * h2 * w2;
        float v = m00 * im[o00] + m10 * im[o10] + m01 * im[o01] + m11 * im[o11];
        outb[(size_t)(32 + ch) * HW] = v;
    }
}

// Direct 3x3 conv, pad=1. One thread per output element.
template <int STRIDE, bool RELU>
__global__ void conv3x3_kernel(const float* __restrict__ in, const float* __restrict__ w,
                               const float* __restrict__ bias, float* __restrict__ out,
                               int N, int Cin, int Cout, int IH, int IW)
{
    int OH = IH / STRIDE, OW = IW / STRIDE;
    int idx = blockIdx.x * blockDim.x + threadIdx.x;
    int total = N * Cout * OH * OW;
    if (idx >= total) return;
    int ox = idx % OW;
    int t = idx / OW;
    int oy = t % OH;
    t /= OH;
    int oc = t % Cout;
    int n = t / Cout;

    float acc = bias[oc];
    const float* inb = in + (size_t)n * Cin * IH * IW;
    const float* wb  = w + (size_t)oc * Cin * 9;
    int cy = oy * STRIDE, cx = ox * STRIDE;

    for (int ic = 0; ic < Cin; ++ic) {
        const float* ip = inb + (size_t)ic * IH * IW;
        const float* wp = wb + ic * 9;
        #pragma unroll
        for (int ky = 0; ky < 3; ++ky) {
            int iy = cy + ky - 1;
            if (iy < 0 || iy >= IH) continue;
            #pragma unroll
            for (int kx = 0; kx < 3; ++kx) {
                int ix = cx + kx - 1;
                if (ix < 0 || ix >= IW) continue;
                acc = fmaf(ip[(size_t)iy * IW + ix], wp[ky * 3 + kx], acc);
            }
        }
    }
    if (RELU) acc = fmaxf(acc, 0.f);
    out[idx] = acc;
}

// ConvTranspose2d(64->32, k=4, s=2, p=1) per the reference's lhs-dilated conv
// (no kernel flip): out[oy,ox] += in[(oy+ky-2)/2,(ox+kx-2)/2] * w[oc][ic][ky][kx]
// whenever (oy+ky) and (ox+kx) are even and indices in range. ReLU fused.
__global__ void deconv4x4_kernel(const float* __restrict__ in, const float* __restrict__ w,
                                 const float* __restrict__ bias, float* __restrict__ out,
                                 int N)
{
    constexpr int IH = 24, IW = 32, OHs = 48, OWs = 64;
    int idx = blockIdx.x * blockDim.x + threadIdx.x;
    int total = N * 32 * OHs * OWs;
    if (idx >= total) return;
    int ox = idx % OWs;
    int t = idx / OWs;
    int oy = t % OHs;
    t /= OHs;
    int oc = t % 32;
    int n = t / 32;

    float acc = bias[oc];
    const float* inb = in + (size_t)n * 64 * IH * IW;
    for (int ic = 0; ic < 64; ++ic) {
        const float* ip = inb + (size_t)ic * IH * IW;
        const float* wp = w + ((size_t)oc * 64 + ic) * 16;
        #pragma unroll
        for (int ky = 0; ky < 4; ++ky) {
            int ty = oy + ky - 2;
            if (ty & 1) continue;
            int iy = ty >> 1;
            if (iy < 0 || iy >= IH) continue;
            #pragma unroll
            for (int kx = 0; kx < 4; ++kx) {
                int tx = ox + kx - 2;
                if (tx & 1) continue;
                int ix = tx >> 1;
                if (ix < 0 || ix >= IW) continue;
                acc = fmaf(ip[(size_t)iy * IW + ix], wp[ky * 4 + kx], acc);
            }
        }
    }
    acc = fmaxf(acc, 0.f);
    out[idx] = acc;
}

// DAP: out[b, lvl*81+o, :, :] = sum_c dapw[o,c] * cost[b*81+c, :, :]
__global__ void dap_kernel(const float* __restrict__ cost, const float* __restrict__ dapw,
                           float* __restrict__ out, int lvl)
{
    int idx = blockIdx.x * blockDim.x + threadIdx.x;
    int total = NB * 81 * HW;
    if (idx >= total) return;
    int px = idx % HW;
    int t = idx / HW;
    int o = t % 81;
    int b = t / 81;
    const float* dw = dapw + (size_t)o * 81;
    const float* cb = cost + (size_t)b * 81 * HW + px;
    float acc = 0.f;
    #pragma unroll 9
    for (int c = 0; c < 81; ++c) acc = fmaf(dw[c], cb[(size_t)c * HW], acc);
    out[((size_t)(b * 4 * 81 + lvl * 81 + o)) * HW + px] = acc;
}

extern "C" void kernel_launch(void* const* d_in, const int* in_sizes, int n_in,
                              void* d_out, int out_size, void* d_ws, size_t ws_size,
                              hipStream_t stream)
{
    // Interleaved input order (see header comment).
    const float* f1[4] = {(const float*)d_in[0], (const float*)d_in[2],
                          (const float*)d_in[4], (const float*)d_in[6]};
    const float* f2[4] = {(const float*)d_in[1], (const float*)d_in[3],
                          (const float*)d_in[5], (const float*)d_in[7]};
    const float* coords = (const float*)d_in[8];
    const float* mw1 = (const float*)d_in[9];
    const float* mb1 = (const float*)d_in[10];
    const float* mw2 = (const float*)d_in[11];
    const float* mb2 = (const float*)d_in[12];
    const float* mw3 = (const float*)d_in[13];
    const float* mb3 = (const float*)d_in[14];
    const float* mw4 = (const float*)d_in[15];
    const float* mb4 = (const float*)d_in[16];
    const float* mw5 = (const float*)d_in[17];
    const float* mb5 = (const float*)d_in[18];
    const float* mw6 = (const float*)d_in[19];
    const float* mb6 = (const float*)d_in[20];
    const float* dapw = (const float*)d_in[21];
    float* out = (float*)d_out;

    // Workspace partition: region A (corr/x2/x4), region B (x1/x3/x5),
    // plus a persistent full-cost buffer for the level's DAP.
    const size_t perA = (size_t)64 * HW * sizeof(float);   // 768 KiB / image
    const size_t perB = (size_t)96 * HW * sizeof(float);   // 1.125 MiB / image
    const size_t costBytes = (size_t)NIMG * HW * sizeof(float);
    static const int divs[10] = {162, 81, 54, 27, 18, 9, 6, 3, 2, 1};
    int chunk = 1;
    for (int i = 0; i < 10; ++i) {
        size_t need = (size_t)divs[i] * (perA + perB) + costBytes + 1024;
        if (need <= ws_size) { chunk = divs[i]; break; }
    }

    char* wsb = (char*)d_ws;
    size_t offA = 0;
    size_t offB = ((size_t)chunk * perA + 255) / 256 * 256;
    size_t offC = offB + ((size_t)chunk * perB + 255) / 256 * 256;
    float* bufA = (float*)(wsb + offA);
    float* bufB = (float*)(wsb + offB);
    float* cost = (float*)(wsb + offC);

    const int TPB = 256;

    for (int lvl = 0; lvl < 4; ++lvl) {
        int h2 = HH >> lvl, w2 = WW >> lvl;
        float inv_scale = 1.0f / (float)(1 << lvl);
        const float* w1 = mw1 + (size_t)lvl * 96 * 64 * 9;
        const float* b1 = mb1 + (size_t)lvl * 96;
        const float* w2p = mw2 + (size_t)lvl * 128 * 96 * 9;
        const float* b2 = mb2 + (size_t)lvl * 128;
        const float* w3 = mw3 + (size_t)lvl * 128 * 128 * 9;
        const float* b3 = mb3 + (size_t)lvl * 128;
        const float* w4 = mw4 + (size_t)lvl * 64 * 128 * 9;
        const float* b4 = mb4 + (size_t)lvl * 64;
        const float* w5 = mw5 + (size_t)lvl * 32 * 64 * 16;
        const float* b5 = mb5 + (size_t)lvl * 32;
        const float* w6 = mw6 + (size_t)lvl * 1 * 32 * 9;
        const float* b6 = mb6 + (size_t)lvl * 1;

        for (int n0 = 0; n0 < NIMG; n0 += chunk) {
            int n = chunk;
            // 1) build corr [n, 64, 48, 64] in A
            {
                int total = n * HW;
                sample_kernel<<<cdiv(total, TPB), TPB, 0, stream>>>(
                    f1[lvl], f2[lvl], coords, bufA, n0, n, h2, w2, inv_scale);
            }
            // 2) conv1 64->96 relu: A -> B   (48x64)
            {
                int total = n * 96 * HW;
                conv3x3_kernel<1, true><<<cdiv(total, TPB), TPB, 0, stream>>>(
                    bufA, w1, b1, bufB, n, 64, 96, HH, WW);
            }
            // 3) conv2 96->128 stride2 relu: B -> A  (24x32)
            {
                int total = n * 128 * (HW / 4);
                conv3x3_kernel<2, true><<<cdiv(total, TPB), TPB, 0, stream>>>(
                    bufB, w2p, b2, bufA, n, 96, 128, HH, WW);
            }
            // 4) conv3 128->128 relu: A -> B  (24x32)
            {
                int total = n * 128 * (HW / 4);
                conv3x3_kernel<1, true><<<cdiv(total, TPB), TPB, 0, stream>>>(
                    bufA, w3, b3, bufB, n, 128, 128, HH / 2, WW / 2);
            }
            // 5) conv4 128->64 relu: B -> A  (24x32)
            {
                int total = n * 64 * (HW / 4);
                conv3x3_kernel<1, true><<<cdiv(total, TPB), TPB, 0, stream>>>(
                    bufB, w4, b4, bufA, n, 128, 64, HH / 2, WW / 2);
            }
            // 6) deconv 64->32 relu: A -> B  (48x64)
            {
                int total = n * 32 * HW;
                deconv4x4_kernel<<<cdiv(total, TPB), TPB, 0, stream>>>(
                    bufA, w5, b5, bufB, n);
            }
            // 7) conv6 32->1: B -> cost[n0..]  (48x64)
            {
                int total = n * 1 * HW;
                conv3x3_kernel<1, false><<<cdiv(total, TPB), TPB, 0, stream>>>(
                    bufB, w6, b6, cost + (size_t)n0 * HW, n, 32, 1, HH, WW);
            }
        }
        // 8) DAP for this level
        {
            int total = NB * 81 * HW;
            dap_kernel<<<cdiv(total, TPB), TPB, 0, stream>>>(cost, dapw + (size_t)lvl * 81 * 81, out, lvl);
        }
    }
}

// Round 3
// 10341.486 us; speedup vs baseline: 10.1993x; 10.1993x over previous
//
#include <hip/hip_runtime.h>

// ---------------------------------------------------------------------------
// RAFT+DICL correlation module — fp32, register-tiled K-major convs.
// All matching-net shapes identical across levels: 48x64 / 24x32.
// Input order is INTERLEAVED: d_in[0]=fmap1_0, d_in[1]=fmap2_0, ...
// ---------------------------------------------------------------------------

constexpr int D9 = 9, NB = 2, HH = 48, WW = 64;
constexpr int NIMG = NB * D9 * D9;       // 162
constexpr int HW = HH * WW;              // 3072
constexpr int H2 = 24, W2 = 32, HW2 = H2 * W2;  // 768

// K-major transposed weight sizes (per level)
constexpr int K1 = 576,  OC1 = 96;
constexpr int K2 = 864,  OC2 = 128;
constexpr int K3 = 1152, OC3 = 128;
constexpr int K4 = 1152, OC4 = 64;
constexpr int K5 = 256,  OC5 = 32;       // per parity class, 4 classes
constexpr int BT1 = 0;
constexpr int BT2 = BT1 + K1 * OC1;      // 55296
constexpr int BT3 = BT2 + K2 * OC2;      // 165888
constexpr int BT4 = BT3 + K3 * OC3;      // 313344
constexpr int BT5 = BT4 + K4 * OC4;      // 387072
constexpr int WL  = BT5 + 4 * K5 * OC5;  // 419840 floats per level

static inline int cdiv(int a, int b) { return (a + b - 1) / b; }

// ---------------- weight prep ----------------
// [L][OC][K] -> [L][K][OC] (dst levels strided by WL, base pre-offset)
__global__ void transpose_w(const float* __restrict__ w, float* __restrict__ wT,
                            int OC, int K, int dstStride)
{
    int idx = blockIdx.x * blockDim.x + threadIdx.x;
    int tot = 4 * OC * K;
    if (idx >= tot) return;
    int lvl = idx / (OC * K);
    int r = idx - lvl * OC * K;
    int oc = r / K;
    int k = r - oc * K;
    wT[(size_t)lvl * dstStride + (size_t)k * OC + oc] = w[idx];
}

// deconv weights [L][32][64][4][4] -> per parity class (p,q): [ic][u][v][oc]
// ky = p + 2u, kx = q + 2v.
__global__ void transpose_w5(const float* __restrict__ w5, float* __restrict__ wT5,
                             int dstStride)
{
    int idx = blockIdx.x * blockDim.x + threadIdx.x;
    if (idx >= 4 * 32 * 64 * 16) return;
    int t  = idx & 15;
    int ic = (idx >> 4) & 63;
    int oc = (idx >> 10) & 31;
    int lvl = idx >> 15;
    int ky = t >> 2, kx = t & 3;
    int p = ky & 1, u = ky >> 1, q = kx & 1, v = kx >> 1;
    wT5[(size_t)lvl * dstStride + (((p * 2 + q) * K5 + (ic * 4 + u * 2 + v)) * OC5 + oc)] = w5[idx];
}

// ---------------- sampling ----------------
__global__ void sample_kernel(const float* __restrict__ f1, const float* __restrict__ f2,
                              const float* __restrict__ coords, float* __restrict__ corr,
                              int n0, int nimg, int h2, int w2, float inv_scale)
{
    int idx = blockIdx.x * blockDim.x + threadIdx.x;
    int total = nimg * HW;
    if (idx >= total) return;
    int x = idx % WW;
    int t = idx / WW;
    int y = t % HH;
    int nl = t / HH;
    int ng = n0 + nl;
    int b = ng / (D9 * D9);
    int c81 = ng % (D9 * D9);
    int di = c81 / D9;
    int dj = c81 % D9;

    float cx = coords[((size_t)(b * 2 + 0) * HH + y) * WW + x];
    float cy = coords[((size_t)(b * 2 + 1) * HH + y) * WW + x];
    float gx = cx * inv_scale + (float)(di - 4);
    float gy = cy * inv_scale + (float)(dj - 4);

    float x0f = floorf(gx), y0f = floorf(gy);
    float wx = gx - x0f, wy = gy - y0f;
    int x0 = (int)x0f, y0 = (int)y0f;
    int x1 = x0 + 1, y1 = y0 + 1;
    bool vx0 = (x0 >= 0) && (x0 <= w2 - 1);
    bool vx1 = (x1 >= 0) && (x1 <= w2 - 1);
    bool vy0 = (y0 >= 0) && (y0 <= h2 - 1);
    bool vy1 = (y1 >= 0) && (y1 <= h2 - 1);
    int xc0 = min(max(x0, 0), w2 - 1), xc1 = min(max(x1, 0), w2 - 1);
    int yc0 = min(max(y0, 0), h2 - 1), yc1 = min(max(y1, 0), h2 - 1);
    float m00 = (vx0 && vy0) ? (1.f - wx) * (1.f - wy) : 0.f;
    float m10 = (vx1 && vy0) ? wx * (1.f - wy) : 0.f;
    float m01 = (vx0 && vy1) ? (1.f - wx) * wy : 0.f;
    float m11 = (vx1 && vy1) ? wx * wy : 0.f;

    const float* f1b = f1 + ((size_t)b * 32) * HW + (size_t)y * WW + x;
    const float* f2b = f2 + (size_t)b * 32 * h2 * w2;
    float* outb = corr + (size_t)nl * 64 * HW + (size_t)y * WW + x;

    #pragma unroll 8
    for (int ch = 0; ch < 32; ++ch)
        outb[(size_t)ch * HW] = f1b[(size_t)ch * HW];

    int o00 = yc0 * w2 + xc0, o10 = yc0 * w2 + xc1;
    int o01 = yc1 * w2 + xc0, o11 = yc1 * w2 + xc1;
    #pragma unroll 4
    for (int ch = 0; ch < 32; ++ch) {
        const float* im = f2b + (size_t)ch * h2 * w2;
        float v = m00 * im[o00] + m10 * im[o10] + m01 * im[o01] + m11 * im[o11];
        outb[(size_t)(32 + ch) * HW] = v;
    }
}

// ---------------- K-major register-tiled conv3x3 ----------------
// Weights wT: [K=IC*9][OC], uniform per wave -> scalar loads.
// One thread: 1 output pixel x 16 output channels.
template <int IC, int OC, int IH, int IW, int OH, int OW, int S, bool RELU>
__global__ __launch_bounds__(256)
void conv_km(const float* __restrict__ in, const float* __restrict__ wT,
             const float* __restrict__ bias, float* __restrict__ out)
{
    constexpr int TO = 16;
    constexpr int BR = 256 / OW;
    int tx = threadIdx.x;
    int ox = tx % OW;
    int oy = blockIdx.x * BR + tx / OW;
    int oc0 = blockIdx.y * TO;
    int n = blockIdx.z;

    float acc[TO];
    #pragma unroll
    for (int o = 0; o < TO; ++o) acc[o] = bias[oc0 + o];

    int cx = ox * S, cy = oy * S;
    bool mL = (cx - 1 >= 0), mR = (cx + 1 < IW);
    int xl = mL ? cx - 1 : 0, xr = mR ? cx + 1 : IW - 1;

    const float* ip = in + (size_t)n * IC * IH * IW;
    const float* wk = wT + oc0;

    for (int ic = 0; ic < IC; ++ic) {
        const float* icp = ip + ic * IH * IW;
        const float* wpk = wk + ic * 9 * OC;
        #pragma unroll
        for (int ky = 0; ky < 3; ++ky) {
            int iy = cy + ky - 1;
            if ((unsigned)iy < (unsigned)IH) {
                const float* rp = icp + iy * IW;
                float v0 = rp[xl]; v0 = mL ? v0 : 0.f;
                float v1 = rp[cx];
                float v2 = rp[xr]; v2 = mR ? v2 : 0.f;
                const float* wp = wpk + ky * 3 * OC;
                #pragma unroll
                for (int o = 0; o < TO; ++o) acc[o] = fmaf(v0, wp[o], acc[o]);
                #pragma unroll
                for (int o = 0; o < TO; ++o) acc[o] = fmaf(v1, wp[OC + o], acc[o]);
                #pragma unroll
                for (int o = 0; o < TO; ++o) acc[o] = fmaf(v2, wp[2 * OC + o], acc[o]);
            }
        }
    }
    float* ob = out + ((size_t)n * OC + oc0) * OH * OW + oy * OW + ox;
    #pragma unroll
    for (int o = 0; o < TO; ++o) {
        float r = acc[o];
        if (RELU) r = fmaxf(r, 0.f);
        ob[(size_t)o * OH * OW] = r;
    }
}

// ---------------- deconv (4 parity classes, 2x2 taps, K-major) ----------------
// out(2a+p, 2b+q) = relu(b5 + sum_{ic,u,v} in[ic][a+p-1+u][b+q-1+v] * wc[(ic,u,v)][oc])
// One wave per parity class -> weights wave-uniform.
__global__ __launch_bounds__(256)
void deconv_km(const float* __restrict__ in, const float* __restrict__ wT5,
               const float* __restrict__ bias, float* __restrict__ out)
{
    constexpr int TO = 16;
    int tx = threadIdx.x;
    int wv = tx >> 6;
    int p = wv >> 1, q = wv & 1;
    int lane = tx & 63;
    int a = blockIdx.x * 2 + (lane >> 5);
    int b = lane & 31;
    int oc0 = blockIdx.y * TO;
    int n = blockIdx.z;

    float acc[TO];
    #pragma unroll
    for (int o = 0; o < TO; ++o) acc[o] = bias[oc0 + o];

    int iy0 = a + p - 1, iy1 = a + p;
    int ix0 = b + q - 1, ix1 = b + q;
    bool my0 = iy0 >= 0, my1 = iy1 <= H2 - 1, mx0 = ix0 >= 0, mx1 = ix1 <= W2 - 1;
    int cy0 = my0 ? iy0 : 0, cy1 = my1 ? iy1 : H2 - 1;
    int cx0 = mx0 ? ix0 : 0, cx1 = mx1 ? ix1 : W2 - 1;

    const float* ib = in + (size_t)n * 64 * HW2;
    const float* wc = wT5 + ((p * 2 + q) * K5) * OC5 + oc0;

    for (int ic = 0; ic < 64; ++ic) {
        const float* icp = ib + ic * HW2;
        float v00 = icp[cy0 * W2 + cx0]; v00 = (my0 && mx0) ? v00 : 0.f;
        float v01 = icp[cy0 * W2 + cx1]; v01 = (my0 && mx1) ? v01 : 0.f;
        float v10 = icp[cy1 * W2 + cx0]; v10 = (my1 && mx0) ? v10 : 0.f;
        float v11 = icp[cy1 * W2 + cx1]; v11 = (my1 && mx1) ? v11 : 0.f;
        const float* wp = wc + ic * 4 * OC5;
        #pragma unroll
        for (int o = 0; o < TO; ++o) acc[o] = fmaf(v00, wp[o], acc[o]);
        #pragma unroll
        for (int o = 0; o < TO; ++o) acc[o] = fmaf(v01, wp[OC5 + o], acc[o]);
        #pragma unroll
        for (int o = 0; o < TO; ++o) acc[o] = fmaf(v10, wp[2 * OC5 + o], acc[o]);
        #pragma unroll
        for (int o = 0; o < TO; ++o) acc[o] = fmaf(v11, wp[3 * OC5 + o], acc[o]);
    }
    int oy = 2 * a + p, ox = 2 * b + q;
    float* ob = out + ((size_t)n * 32 + oc0) * HW + oy * WW + ox;
    #pragma unroll
    for (int o = 0; o < TO; ++o) ob[(size_t)o * HW] = fmaxf(acc[o], 0.f);
}

// ---------------- conv6 (32->1) ----------------
__global__ void conv6_kernel(const float* __restrict__ in, const float* __restrict__ w6,
                             const float* __restrict__ b6, float* __restrict__ cost,
                             int n0, int nimg)
{
    int idx = blockIdx.x * blockDim.x + threadIdx.x;
    if (idx >= nimg * HW) return;
    int x = idx % WW;
    int t = idx / WW;
    int y = t % HH;
    int nl = t / HH;
    float acc = b6[0];
    const float* ib = in + (size_t)nl * 32 * HW;
    bool mL = x >= 1, mR = x + 1 < WW;
    int xl = mL ? x - 1 : 0, xr = mR ? x + 1 : WW - 1;
    for (int ic = 0; ic < 32; ++ic) {
        const float* icp = ib + ic * HW;
        #pragma unroll
        for (int ky = 0; ky < 3; ++ky) {
            int iy = y + ky - 1;
            if ((unsigned)iy < (unsigned)HH) {
                const float* rp = icp + iy * WW;
                float v0 = rp[xl]; v0 = mL ? v0 : 0.f;
                float v1 = rp[x];
                float v2 = rp[xr]; v2 = mR ? v2 : 0.f;
                const float* wp = w6 + ic * 9 + ky * 3;
                acc = fmaf(v0, wp[0], acc);
                acc = fmaf(v1, wp[1], acc);
                acc = fmaf(v2, wp[2], acc);
            }
        }
    }
    cost[(size_t)(n0 + nl) * HW + y * WW + x] = acc;
}

// ---------------- DAP ----------------
__global__ void dap_kernel(const float* __restrict__ cost, const float* __restrict__ dapw,
                           float* __restrict__ out, int lvl)
{
    int idx = blockIdx.x * blockDim.x + threadIdx.x;
    int total = NB * 81 * HW;
    if (idx >= total) return;
    int px = idx % HW;
    int t = idx / HW;
    int o = t % 81;
    int b = t / 81;
    const float* dw = dapw + (size_t)o * 81;
    const float* cb = cost + (size_t)b * 81 * HW + px;
    float acc = 0.f;
    #pragma unroll 9
    for (int c = 0; c < 81; ++c) acc = fmaf(dw[c], cb[(size_t)c * HW], acc);
    out[((size_t)(b * 4 * 81 + lvl * 81 + o)) * HW + px] = acc;
}

// ---------------------------------------------------------------------------
extern "C" void kernel_launch(void* const* d_in, const int* in_sizes, int n_in,
                              void* d_out, int out_size, void* d_ws, size_t ws_size,
                              hipStream_t stream)
{
    const float* f1[4] = {(const float*)d_in[0], (const float*)d_in[2],
                          (const float*)d_in[4], (const float*)d_in[6]};
    const float* f2[4] = {(const float*)d_in[1], (const float*)d_in[3],
                          (const float*)d_in[5], (const float*)d_in[7]};
    const float* coords = (const float*)d_in[8];
    const float* mw1 = (const float*)d_in[9];
    const float* mb1 = (const float*)d_in[10];
    const float* mw2 = (const float*)d_in[11];
    const float* mb2 = (const float*)d_in[12];
    const float* mw3 = (const float*)d_in[13];
    const float* mb3 = (const float*)d_in[14];
    const float* mw4 = (const float*)d_in[15];
    const float* mb4 = (const float*)d_in[16];
    const float* mw5 = (const float*)d_in[17];
    const float* mb5 = (const float*)d_in[18];
    const float* mw6 = (const float*)d_in[19];
    const float* mb6 = (const float*)d_in[20];
    const float* dapw = (const float*)d_in[21];
    float* out = (float*)d_out;

    // ws layout: weights | cost | bufA | bufB
    const size_t wFloats = (size_t)4 * WL;
    const size_t wBytes = (wFloats * 4 + 255) / 256 * 256;
    const size_t costBytes = ((size_t)NIMG * HW * 4 + 255) / 256 * 256;
    const size_t SA = (size_t)64 * HW * 4;   // max stage in A: corr
    const size_t SB = (size_t)96 * HW * 4;   // max stage in B: x1

    static const int divs[10] = {162, 81, 54, 27, 18, 9, 6, 3, 2, 1};
    int chunk = 1;
    for (int i = 0; i < 10; ++i) {
        size_t need = wBytes + costBytes + (size_t)divs[i] * (SA + SB) + 1024;
        if (need <= ws_size) { chunk = divs[i]; break; }
    }

    char* wsb = (char*)d_ws;
    float* wsW = (float*)wsb;
    float* cost = (float*)(wsb + wBytes);
    float* bufA = (float*)(wsb + wBytes + costBytes);
    float* bufB = (float*)(wsb + wBytes + costBytes + (size_t)chunk * SA);

    const int TPB = 256;

    // one-time weight transposes (all 4 levels each)
    transpose_w<<<cdiv(4 * OC1 * K1, TPB), TPB, 0, stream>>>(mw1, wsW + BT1, OC1, K1, WL);
    transpose_w<<<cdiv(4 * OC2 * K2, TPB), TPB, 0, stream>>>(mw2, wsW + BT2, OC2, K2, WL);
    transpose_w<<<cdiv(4 * OC3 * K3, TPB), TPB, 0, stream>>>(mw3, wsW + BT3, OC3, K3, WL);
    transpose_w<<<cdiv(4 * OC4 * K4, TPB), TPB, 0, stream>>>(mw4, wsW + BT4, OC4, K4, WL);
    transpose_w5<<<cdiv(4 * 32 * 64 * 16, TPB), TPB, 0, stream>>>(mw5, wsW + BT5, WL);

    for (int lvl = 0; lvl < 4; ++lvl) {
        int h2 = HH >> lvl, w2 = WW >> lvl;
        float inv_scale = 1.0f / (float)(1 << lvl);
        const float* wT = wsW + (size_t)lvl * WL;
        const float* b1 = mb1 + (size_t)lvl * 96;
        const float* b2 = mb2 + (size_t)lvl * 128;
        const float* b3 = mb3 + (size_t)lvl * 128;
        const float* b4 = mb4 + (size_t)lvl * 64;
        const float* b5 = mb5 + (size_t)lvl * 32;
        const float* w6 = mw6 + (size_t)lvl * 288;
        const float* b6 = mb6 + (size_t)lvl * 1;

        for (int n0 = 0; n0 < NIMG; n0 += chunk) {
            int n = chunk;
            sample_kernel<<<cdiv(n * HW, TPB), TPB, 0, stream>>>(
                f1[lvl], f2[lvl], coords, bufA, n0, n, h2, w2, inv_scale);
            // conv1 64->96 relu (48x64): A -> B
            conv_km<64, 96, 48, 64, 48, 64, 1, true><<<dim3(12, 6, n), TPB, 0, stream>>>(
                bufA, wT + BT1, b1, bufB);
            // conv2 96->128 s2 relu (48x64 -> 24x32): B -> A
            conv_km<96, 128, 48, 64, 24, 32, 2, true><<<dim3(3, 8, n), TPB, 0, stream>>>(
                bufB, wT + BT2, b2, bufA);
            // conv3 128->128 relu (24x32): A -> B
            conv_km<128, 128, 24, 32, 24, 32, 1, true><<<dim3(3, 8, n), TPB, 0, stream>>>(
                bufA, wT + BT3, b3, bufB);
            // conv4 128->64 relu (24x32): B -> A
            conv_km<128, 64, 24, 32, 24, 32, 1, true><<<dim3(3, 4, n), TPB, 0, stream>>>(
                bufB, wT + BT4, b4, bufA);
            // deconv 64->32 relu (24x32 -> 48x64): A -> B
            deconv_km<<<dim3(12, 2, n), TPB, 0, stream>>>(bufA, wT + BT5, b5, bufB);
            // conv6 32->1 (48x64): B -> cost
            conv6_kernel<<<cdiv(n * HW, TPB), TPB, 0, stream>>>(bufB, w6, b6, cost, n0, n);
        }
        dap_kernel<<<cdiv(NB * 81 * HW, TPB), TPB, 0, stream>>>(
            cost, dapw + (size_t)lvl * 81 * 81, out, lvl);
    }
}